// Round 2
// baseline (485.953 us; speedup 1.0000x reference)
//
#include <hip/hip_runtime.h>
#include <cstdint>

#define NSTEP 1000
#define NELEM 45056          // 16 * 1 * 64 * 44
#define HW    2816           // 64 * 44
#define WS_NEED (sizeof(float) * (size_t)NSTEP * (size_t)NELEM)

// ---------- compile-time fp64 DDIM schedule (bit-exact vs np.linspace+cumprod) ----------
struct AlphTab { float a[NSTEP + 1]; };

constexpr AlphTab make_alph() {
    AlphTab t{};
    t.a[0] = 1.0f;
    double alph = 1.0;
    const double start = 1e-4, stop = 0.02;
    const double step = (stop - start) / 999.0;   // np.linspace step in f64
    for (int i = 0; i < NSTEP; ++i) {
        double beta = (i == NSTEP - 1) ? stop : ((double)i * step + start); // y[-1]=stop
        alph *= (1.0 - beta);
        t.a[i + 1] = (float)alph;                 // astype(float32)
    }
    return t;
}
constexpr AlphTab ALPH = make_alph();

// ---------- Threefry-2x32-20 (jax threefry2x32_p) ----------
__device__ __forceinline__ void tf20(uint32_t K0, uint32_t K1, uint32_t K2,
                                     uint32_t& x0, uint32_t& x1) {
    x0 += K0; x1 += K1;
#define TFR(r) { x0 += x1; x1 = ((x1 << r) | (x1 >> (32 - r))); x1 ^= x0; }
    TFR(13) TFR(15) TFR(26) TFR(6)
    x0 += K1; x1 += K2 + 1u;
    TFR(17) TFR(29) TFR(16) TFR(24)
    x0 += K2; x1 += K0 + 2u;
    TFR(13) TFR(15) TFR(26) TFR(6)
    x0 += K0; x1 += K1 + 3u;
    TFR(17) TFR(29) TFR(16) TFR(24)
    x0 += K1; x1 += K2 + 4u;
    TFR(13) TFR(15) TFR(26) TFR(6)
    x0 += K2; x1 += K0 + 5u;
#undef TFR
}

__device__ __forceinline__ float fast_tanh(float x) {
    const float e2 = __expf(x + x);
    const float r  = __builtin_amdgcn_rcpf(e2 + 1.0f);
    return fmaf(-2.0f, r, 1.0f);                  // 1 - 2/(e^{2x}+1)
}

// =====================================================================
// Kernel A: fully-parallel RNG + drift precompute.
//   d[k*NELEM + j] = sqrt2*c1_k * erfinv(u_{k,j}) + e_k * silT[j]
// grid = (NELEM/256, NSTEP); one thread per (k, j).
// =====================================================================
__global__ __launch_bounds__(256)
void rng_kernel(const float* __restrict__ silT, float* __restrict__ dws) {
    const int k = (int)blockIdx.y;               // scan-step index
    const int t = 999 - k;                       // DDIM timestep (reversed)

    // wave-uniform schedule constants (SALU-friendly: depend only on blockIdx.y)
    const float at  = ALPH.a[t + 1];
    const float atn = ALPH.a[t];
    const float c1 = 0.1f * sqrtf((1.0f - at / atn) * (1.0f - atn) / (1.0f - at));
    const float c2 = sqrtf(fmaxf(1.0f - atn - c1 * c1, 0.0f));
    const float rs = 1.0f / sqrtf(1.0f - at);
    const float e  = c2 * rs;
    const float c1s = c1 * 1.4142135f;           // fold sqrt(2) into c1

    // fold_in(key(42), t): threefry((0,42), (0,t)) — wave-uniform
    uint32_t k0 = 0u, k1 = (uint32_t)t;
    tf20(0u, 42u, 0x1BD11BDAu ^ 42u, k0, k1);
    const uint32_t k2 = k0 ^ k1 ^ 0x1BD11BDAu;

    const int j = (int)(blockIdx.x * 256u + threadIdx.x);

    // partitionable threefry bits: counts (hi,lo) = (0, j); bits = x0 ^ x1
    uint32_t x0 = 0u, x1 = (uint32_t)j;
    tf20(k0, k1, k2, x0, x1);
    const uint32_t bits = x0 ^ x1;

    // XLA uniform in [lo, 1)
    const float f2 = __uint_as_float((bits >> 9) | 0x3F800000u) - 1.0f;
    const float u  = f2 * 2.0f - 0.99999994f;

    // XLA/Giles erfinv (f32)
    const float t1 = (1.0f - u) * (1.0f + u);
    const float w  = __log2f(t1) * -0.6931472f;
    const bool  lt = w < 5.0f;
    const float ww = lt ? (w - 2.5f) : (sqrtf(w) - 3.0f);
    float p =          lt ?  2.81022636e-08f : -0.000200214257f;
    p = fmaf(p, ww,    lt ?  3.43273939e-07f :  0.000100950558f);
    p = fmaf(p, ww,    lt ? -3.5233877e-06f  :  0.00134934322f);
    p = fmaf(p, ww,    lt ? -4.39150654e-06f : -0.00367342844f);
    p = fmaf(p, ww,    lt ?  0.00021858087f  :  0.00573950773f);
    p = fmaf(p, ww,    lt ? -0.00125372503f  : -0.0076224613f);
    p = fmaf(p, ww,    lt ? -0.00417768164f  :  0.00943887047f);
    p = fmaf(p, ww,    lt ?  0.246640727f    :  1.00167406f);
    p = fmaf(p, ww,    lt ?  1.50140941f     :  2.83297682f);

    dws[(size_t)k * NELEM + j] = fmaf(c1s, p * u, e * silT[j]);
}

// =====================================================================
// Kernel B: lightweight sequential scan; d streamed with 8-deep prefetch.
// grid = NELEM/64 blocks of 64 threads (spreads 704 waves over all CUs).
// =====================================================================
__global__ __launch_bounds__(64)
void scan_kernel(const float* __restrict__ skes,
                 const float* __restrict__ silT,
                 const float* __restrict__ wskes,
                 const float* __restrict__ wsil_p,
                 const float* __restrict__ tsc_p,
                 const float* __restrict__ dws,
                 float* __restrict__ out) {
    __shared__ __align__(8) uint2 tab[NSTEP];    // {A, temb*2*log2e}

    const float wsil = wsil_p[0];
    const float tsc  = tsc_p[0];
    const float L2E2 = 2.8853900817779268f;      // 2*log2(e)

    for (int k = (int)threadIdx.x; k < NSTEP; k += 64) {
        const int t = 999 - k;
        const float at  = ALPH.a[t + 1];
        const float atn = ALPH.a[t];
        const float c1 = 0.1f * sqrtf((1.0f - at / atn) * (1.0f - atn) / (1.0f - at));
        const float c2 = sqrtf(fmaxf(1.0f - atn - c1 * c1, 0.0f));
        const float rs = 1.0f / sqrtf(1.0f - at);
        const float A  = sqrtf(atn) - c2 * sqrtf(at) * rs;
        const float temb = tsc * ((float)t / 1000.0f);
        tab[k] = make_uint2(__float_as_uint(A), __float_as_uint(temb * L2E2));
    }
    __syncthreads();

    const int j  = (int)(blockIdx.x * 64u + threadIdx.x);
    const int ns = j / HW;
    const int hw = j - ns * HW;
    const int n  = ns >> 3;
    const int ss = ns & 7;
    const float* sk = skes + (size_t)((n * 3) * 8 + ss) * HW + hw;
    const float w0 = wskes[0], w1 = wskes[1], w2 = wskes[2];
    const float cond  = fmaf(w2, sk[2 * 8 * HW], fmaf(w1, sk[8 * HW], w0 * sk[0]));
    const float cond2 = cond * L2E2;             // pre-scaled for exp2 tanh
    const float ws2   = wsil * L2E2;

    float sil = silT[j];
    float* op = out + j;
    const float* dp = dws + j;

    float cur[8], nxt[8];
#pragma unroll
    for (int i = 0; i < 8; ++i) cur[i] = dp[(size_t)i * NELEM];
    dp += (size_t)8 * NELEM;

#pragma unroll 1
    for (int kk = 0; kk < NSTEP; kk += 8) {
        if (kk + 8 < NSTEP) {                    // prefetch next chunk
#pragma unroll
            for (int i = 0; i < 8; ++i) nxt[i] = dp[(size_t)i * NELEM];
            dp += (size_t)8 * NELEM;
        }
#pragma unroll
        for (int i = 0; i < 8; ++i) {
            const uint2 tt = tab[kk + i];
            const float A    = __uint_as_float(tt.x);
            const float ct2  = cond2 + __uint_as_float(tt.y);
            // tanh(x) = 1 - 2/(exp2(x*2*log2e)+1), x = wsil*sil + cond + temb
            const float e2 = __builtin_amdgcn_exp2f(fmaf(ws2, sil, ct2));
            const float r  = __builtin_amdgcn_rcpf(e2 + 1.0f);
            const float s0 = fmaf(-2.0f, r, 1.0f);
            *op = s0; op += NELEM;
            sil = fmaf(A, s0, cur[i]);
        }
#pragma unroll
        for (int i = 0; i < 8; ++i) cur[i] = nxt[i];
    }
}

// =====================================================================
// Fallback: monolithic kernel (used only if ws_size is too small).
// =====================================================================
__global__ __launch_bounds__(256)
void diffgait_mono(const float* __restrict__ skes,
                   const float* __restrict__ silT,
                   const float* __restrict__ wskes,
                   const float* __restrict__ wsil_p,
                   const float* __restrict__ tsc_p,
                   float* __restrict__ out) {
    __shared__ __align__(16) uint32_t tab[NSTEP][8];
    const float wsil = wsil_p[0];
    const float tsc  = tsc_p[0];
    for (int k = (int)threadIdx.x; k < NSTEP; k += 256) {
        const int t = 999 - k;
        const float at  = ALPH.a[t + 1];
        const float atn = ALPH.a[t];
        const float c1 = 0.1f * sqrtf((1.0f - at / atn) * (1.0f - atn) / (1.0f - at));
        const float c2 = sqrtf(fmaxf(1.0f - atn - c1 * c1, 0.0f));
        const float rs = 1.0f / sqrtf(1.0f - at);
        const float A  = sqrtf(atn) - c2 * sqrtf(at) * rs;
        const float e  = c2 * rs;
        const float temb = tsc * ((float)t / 1000.0f);
        uint32_t x0 = 0u, x1 = (uint32_t)t;
        tf20(0u, 42u, 0x1BD11BDAu ^ 42u, x0, x1);
        tab[k][0] = __float_as_uint(A);
        tab[k][1] = __float_as_uint(temb);
        tab[k][2] = __float_as_uint(c1);
        tab[k][3] = __float_as_uint(e);
        tab[k][4] = x0;
        tab[k][5] = x1;
        tab[k][6] = x0 ^ x1 ^ 0x1BD11BDAu;
        tab[k][7] = 0u;
    }
    __syncthreads();
    const int j  = (int)(blockIdx.x * 256u + threadIdx.x);
    const int ns = j / HW;
    const int hw = j - ns * HW;
    const int n  = ns >> 3;
    const int ss = ns & 7;
    const float* sk = skes + (size_t)((n * 3) * 8 + ss) * HW + hw;
    const float w0 = wskes[0], w1 = wskes[1], w2 = wskes[2];
    const float cond = fmaf(w2, sk[2 * 8 * HW], fmaf(w1, sk[8 * HW], w0 * sk[0]));
    const float sT = silT[j];
    float sil = sT;
    float* op = out + j;
#pragma unroll 2
    for (int k = 0; k < NSTEP; ++k) {
        const uint4 ta = *(const uint4*)&tab[k][0];
        const uint4 tb = *(const uint4*)&tab[k][4];
        uint32_t x0 = 0u, x1 = (uint32_t)j;
        tf20(tb.x, tb.y, tb.z, x0, x1);
        const uint32_t bits = x0 ^ x1;
        const float f2 = __uint_as_float((bits >> 9) | 0x3F800000u) - 1.0f;
        const float u  = f2 * 2.0f - 0.99999994f;
        const float t1 = (1.0f - u) * (1.0f + u);
        const float w  = __log2f(t1) * -0.6931472f;
        const bool  lt = w < 5.0f;
        const float ww = lt ? (w - 2.5f) : (sqrtf(w) - 3.0f);
        float p =          lt ?  2.81022636e-08f : -0.000200214257f;
        p = fmaf(p, ww,    lt ?  3.43273939e-07f :  0.000100950558f);
        p = fmaf(p, ww,    lt ? -3.5233877e-06f  :  0.00134934322f);
        p = fmaf(p, ww,    lt ? -4.39150654e-06f : -0.00367342844f);
        p = fmaf(p, ww,    lt ?  0.00021858087f  :  0.00573950773f);
        p = fmaf(p, ww,    lt ? -0.00125372503f  : -0.0076224613f);
        p = fmaf(p, ww,    lt ? -0.00417768164f  :  0.00943887047f);
        p = fmaf(p, ww,    lt ?  0.246640727f    :  1.00167406f);
        p = fmaf(p, ww,    lt ?  1.50140941f     :  2.83297682f);
        const float noise = 1.4142135f * (p * u);
        const float d  = fmaf(__uint_as_float(ta.z), noise, __uint_as_float(ta.w) * sT);
        const float s0 = fast_tanh(fmaf(wsil, sil, cond) + __uint_as_float(ta.y));
        *op = s0; op += NELEM;
        sil = fmaf(__uint_as_float(ta.x), s0, d);
    }
}

extern "C" void kernel_launch(void* const* d_in, const int* in_sizes, int n_in,
                              void* d_out, int out_size, void* d_ws, size_t ws_size,
                              hipStream_t stream) {
    const float* skes = (const float*)d_in[0];
    const float* silT = (const float*)d_in[1];
    const float* wsk  = (const float*)d_in[2];
    const float* wsil = (const float*)d_in[3];
    const float* tsc  = (const float*)d_in[4];
    float* out = (float*)d_out;
    (void)in_sizes; (void)n_in; (void)out_size;

    if (ws_size >= WS_NEED) {
        float* dws = (float*)d_ws;
        dim3 gA(NELEM / 256, NSTEP), bA(256);
        hipLaunchKernelGGL(rng_kernel, gA, bA, 0, stream, silT, dws);
        dim3 gB(NELEM / 64), bB(64);
        hipLaunchKernelGGL(scan_kernel, gB, bB, 0, stream,
                           skes, silT, wsk, wsil, tsc, dws, out);
    } else {
        dim3 grid(NELEM / 256), block(256);
        hipLaunchKernelGGL(diffgait_mono, grid, block, 0, stream,
                           skes, silT, wsk, wsil, tsc, out);
    }
}

// Round 3
// 369.359 us; speedup vs baseline: 1.3157x; 1.3157x over previous
//
#include <hip/hip_runtime.h>
#include <cstdint>

#define NSTEP 1000
#define NELEM 45056          // 16 * 1 * 64 * 44
#define HW    2816           // 64 * 44
#define KPB   20             // k-steps per rng block (NSTEP/KPB grid.y)
#define CH    20             // scan prefetch chunk (NSTEP % (2*CH) == 0)
#define SJ    (NELEM / 2)    // 22528: chain-1 offset in scan
#define WS_NEED (sizeof(float) * (size_t)NSTEP * (size_t)NELEM)

// ---------- compile-time fp64 DDIM schedule (bit-exact vs np.linspace+cumprod) ----------
struct AlphTab { float a[NSTEP + 1]; };

constexpr AlphTab make_alph() {
    AlphTab t{};
    t.a[0] = 1.0f;
    double alph = 1.0;
    const double start = 1e-4, stop = 0.02;
    const double step = (stop - start) / 999.0;
    for (int i = 0; i < NSTEP; ++i) {
        double beta = (i == NSTEP - 1) ? stop : ((double)i * step + start);
        alph *= (1.0 - beta);
        t.a[i + 1] = (float)alph;
    }
    return t;
}
constexpr AlphTab ALPH = make_alph();

// ---------- Threefry-2x32-20 ----------
__device__ __forceinline__ void tf20(uint32_t K0, uint32_t K1, uint32_t K2,
                                     uint32_t& x0, uint32_t& x1) {
    x0 += K0; x1 += K1;
#define TFR(r) { x0 += x1; x1 = ((x1 << r) | (x1 >> (32 - r))); x1 ^= x0; }
    TFR(13) TFR(15) TFR(26) TFR(6)
    x0 += K1; x1 += K2 + 1u;
    TFR(17) TFR(29) TFR(16) TFR(24)
    x0 += K2; x1 += K0 + 2u;
    TFR(13) TFR(15) TFR(26) TFR(6)
    x0 += K0; x1 += K1 + 3u;
    TFR(17) TFR(29) TFR(16) TFR(24)
    x0 += K1; x1 += K2 + 4u;
    TFR(13) TFR(15) TFR(26) TFR(6)
    x0 += K2; x1 += K0 + 5u;
#undef TFR
}

__device__ __forceinline__ float fast_tanh(float x) {
    const float e2 = __expf(x + x);
    const float r  = __builtin_amdgcn_rcpf(e2 + 1.0f);
    return fmaf(-2.0f, r, 1.0f);
}

// =====================================================================
// Kernel A: RNG + drift. grid (NELEM/256, NSTEP/KPB); each block does
// KPB k-steps, schedule constants amortized via a small LDS table.
//   d[k*NELEM + j] = sqrt2*c1_k * erfinv(u_{k,j}) + e_k * silT[j]
// =====================================================================
__global__ __launch_bounds__(256)
void rng_kernel(const float* __restrict__ silT, float* __restrict__ dws) {
    __shared__ __align__(16) uint32_t tab[KPB][8]; // {c1s, e, k0, k1, k2, -, -, -}

    if (threadIdx.x < KPB) {
        const int kl = (int)threadIdx.x;
        const int kg = (int)blockIdx.y * KPB + kl;
        const int t  = 999 - kg;
        const float at  = ALPH.a[t + 1];
        const float atn = ALPH.a[t];
        const float c1 = 0.1f * sqrtf((1.0f - at / atn) * (1.0f - atn) / (1.0f - at));
        const float c2 = sqrtf(fmaxf(1.0f - atn - c1 * c1, 0.0f));
        const float rs = 1.0f / sqrtf(1.0f - at);
        const float e  = c2 * rs;
        uint32_t k0 = 0u, k1 = (uint32_t)t;
        tf20(0u, 42u, 0x1BD11BDAu ^ 42u, k0, k1);
        tab[kl][0] = __float_as_uint(c1 * 1.4142135f);
        tab[kl][1] = __float_as_uint(e);
        tab[kl][2] = k0;
        tab[kl][3] = k1;
        tab[kl][4] = k0 ^ k1 ^ 0x1BD11BDAu;
    }
    __syncthreads();

    const int j = (int)(blockIdx.x * 256u + threadIdx.x);
    const float sT = silT[j];
    float* op = dws + (size_t)((int)blockIdx.y * KPB) * NELEM + j;

#pragma unroll 4
    for (int kk = 0; kk < KPB; ++kk) {
        const uint4 ta    = *(const uint4*)&tab[kk][0];  // c1s, e, k0, k1
        const uint32_t k2 = tab[kk][4];
        const float c1s = __uint_as_float(ta.x);
        const float e   = __uint_as_float(ta.y);

        uint32_t x0 = 0u, x1 = (uint32_t)j;
        tf20(ta.z, ta.w, k2, x0, x1);
        const uint32_t bits = x0 ^ x1;

        const float f2 = __uint_as_float((bits >> 9) | 0x3F800000u) - 1.0f;
        const float u  = f2 * 2.0f - 0.99999994f;

        const float t1 = (1.0f - u) * (1.0f + u);
        const float w  = __log2f(t1) * -0.6931472f;
        const bool  lt = w < 5.0f;
        const float sw = __builtin_amdgcn_sqrtf(w);      // far branch only; 1-ulp ok
        const float ww = lt ? (w - 2.5f) : (sw - 3.0f);
        float p =          lt ?  2.81022636e-08f : -0.000200214257f;
        p = fmaf(p, ww,    lt ?  3.43273939e-07f :  0.000100950558f);
        p = fmaf(p, ww,    lt ? -3.5233877e-06f  :  0.00134934322f);
        p = fmaf(p, ww,    lt ? -4.39150654e-06f : -0.00367342844f);
        p = fmaf(p, ww,    lt ?  0.00021858087f  :  0.00573950773f);
        p = fmaf(p, ww,    lt ? -0.00125372503f  : -0.0076224613f);
        p = fmaf(p, ww,    lt ? -0.00417768164f  :  0.00943887047f);
        p = fmaf(p, ww,    lt ?  0.246640727f    :  1.00167406f);
        p = fmaf(p, ww,    lt ?  1.50140941f     :  2.83297682f);

        *op = fmaf(c1s, p * u, e * sT);
        op += NELEM;
    }
}

// =====================================================================
// Kernel B: sequential scan. 2 independent chains/thread (ILP),
// CH-deep ping-pong register prefetch of d. grid SJ/64 blocks x 64 thr.
// =====================================================================
__global__ __launch_bounds__(64)
void scan_kernel(const float* __restrict__ skes,
                 const float* __restrict__ silT,
                 const float* __restrict__ wskes,
                 const float* __restrict__ wsil_p,
                 const float* __restrict__ tsc_p,
                 const float* __restrict__ dws,
                 float* __restrict__ out) {
    __shared__ __align__(8) uint2 tab[NSTEP];    // {A, temb*2*log2e}

    const float wsil = wsil_p[0];
    const float tsc  = tsc_p[0];
    const float L2E2 = 2.8853900817779268f;      // 2*log2(e)

    for (int k = (int)threadIdx.x; k < NSTEP; k += 64) {
        const int t = 999 - k;
        const float at  = ALPH.a[t + 1];
        const float atn = ALPH.a[t];
        const float c1 = 0.1f * sqrtf((1.0f - at / atn) * (1.0f - atn) / (1.0f - at));
        const float c2 = sqrtf(fmaxf(1.0f - atn - c1 * c1, 0.0f));
        const float rs = 1.0f / sqrtf(1.0f - at);
        const float A  = sqrtf(atn) - c2 * sqrtf(at) * rs;
        const float temb = tsc * ((float)t / 1000.0f);
        tab[k] = make_uint2(__float_as_uint(A), __float_as_uint(temb * L2E2));
    }
    __syncthreads();

    const float w0 = wskes[0], w1 = wskes[1], w2 = wskes[2];
    const float ws2 = wsil * L2E2;

    const int j0 = (int)(blockIdx.x * 64u + threadIdx.x);
    const int j1 = j0 + SJ;

    float c2v[2]; float sil[2];
    int jj[2] = {j0, j1};
#pragma unroll
    for (int q = 0; q < 2; ++q) {
        const int ns = jj[q] / HW;
        const int hw = jj[q] - ns * HW;
        const int n  = ns >> 3;
        const int ss = ns & 7;
        const float* sk = skes + (size_t)((n * 3) * 8 + ss) * HW + hw;
        const float cond = fmaf(w2, sk[2 * 8 * HW], fmaf(w1, sk[8 * HW], w0 * sk[0]));
        c2v[q] = cond * L2E2;
        sil[q] = silT[jj[q]];
    }

    const float* dp0 = dws + j0;
    const float* dp1 = dws + j1;
    float* op0 = out + j0;
    float* op1 = out + j1;

    float A0[CH], A1[CH], B0[CH], B1[CH];
#pragma unroll
    for (int i = 0; i < CH; ++i) {
        A0[i] = dp0[(size_t)i * NELEM];
        A1[i] = dp1[(size_t)i * NELEM];
    }
    dp0 += (size_t)CH * NELEM; dp1 += (size_t)CH * NELEM;

#pragma unroll 1
    for (int kk = 0; kk < NSTEP; kk += 2 * CH) {
        // stage A: prefetch chunk kk+CH into B, compute chunk kk from A
#pragma unroll
        for (int i = 0; i < CH; ++i) {
            B0[i] = dp0[(size_t)i * NELEM];
            B1[i] = dp1[(size_t)i * NELEM];
        }
        dp0 += (size_t)CH * NELEM; dp1 += (size_t)CH * NELEM;
#pragma unroll
        for (int i = 0; i < CH; ++i) {
            const uint2 tt = tab[kk + i];
            const float A  = __uint_as_float(tt.x);
            const float tb = __uint_as_float(tt.y);
            {
                const float e2 = __builtin_amdgcn_exp2f(fmaf(ws2, sil[0], c2v[0] + tb));
                const float r  = __builtin_amdgcn_rcpf(e2 + 1.0f);
                const float s0 = fmaf(-2.0f, r, 1.0f);
                *op0 = s0; op0 += NELEM;
                sil[0] = fmaf(A, s0, A0[i]);
            }
            {
                const float e2 = __builtin_amdgcn_exp2f(fmaf(ws2, sil[1], c2v[1] + tb));
                const float r  = __builtin_amdgcn_rcpf(e2 + 1.0f);
                const float s0 = fmaf(-2.0f, r, 1.0f);
                *op1 = s0; op1 += NELEM;
                sil[1] = fmaf(A, s0, A1[i]);
            }
        }
        // stage B: prefetch chunk kk+2CH into A (if any), compute kk+CH from B
        if (kk + 2 * CH < NSTEP) {
#pragma unroll
            for (int i = 0; i < CH; ++i) {
                A0[i] = dp0[(size_t)i * NELEM];
                A1[i] = dp1[(size_t)i * NELEM];
            }
            dp0 += (size_t)CH * NELEM; dp1 += (size_t)CH * NELEM;
        }
#pragma unroll
        for (int i = 0; i < CH; ++i) {
            const uint2 tt = tab[kk + CH + i];
            const float A  = __uint_as_float(tt.x);
            const float tb = __uint_as_float(tt.y);
            {
                const float e2 = __builtin_amdgcn_exp2f(fmaf(ws2, sil[0], c2v[0] + tb));
                const float r  = __builtin_amdgcn_rcpf(e2 + 1.0f);
                const float s0 = fmaf(-2.0f, r, 1.0f);
                *op0 = s0; op0 += NELEM;
                sil[0] = fmaf(A, s0, B0[i]);
            }
            {
                const float e2 = __builtin_amdgcn_exp2f(fmaf(ws2, sil[1], c2v[1] + tb));
                const float r  = __builtin_amdgcn_rcpf(e2 + 1.0f);
                const float s0 = fmaf(-2.0f, r, 1.0f);
                *op1 = s0; op1 += NELEM;
                sil[1] = fmaf(A, s0, B1[i]);
            }
        }
    }
}

// =====================================================================
// Fallback: monolithic kernel (only if ws_size too small).
// =====================================================================
__global__ __launch_bounds__(256)
void diffgait_mono(const float* __restrict__ skes,
                   const float* __restrict__ silT,
                   const float* __restrict__ wskes,
                   const float* __restrict__ wsil_p,
                   const float* __restrict__ tsc_p,
                   float* __restrict__ out) {
    __shared__ __align__(16) uint32_t tab[NSTEP][8];
    const float wsil = wsil_p[0];
    const float tsc  = tsc_p[0];
    for (int k = (int)threadIdx.x; k < NSTEP; k += 256) {
        const int t = 999 - k;
        const float at  = ALPH.a[t + 1];
        const float atn = ALPH.a[t];
        const float c1 = 0.1f * sqrtf((1.0f - at / atn) * (1.0f - atn) / (1.0f - at));
        const float c2 = sqrtf(fmaxf(1.0f - atn - c1 * c1, 0.0f));
        const float rs = 1.0f / sqrtf(1.0f - at);
        const float A  = sqrtf(atn) - c2 * sqrtf(at) * rs;
        const float e  = c2 * rs;
        const float temb = tsc * ((float)t / 1000.0f);
        uint32_t x0 = 0u, x1 = (uint32_t)t;
        tf20(0u, 42u, 0x1BD11BDAu ^ 42u, x0, x1);
        tab[k][0] = __float_as_uint(A);
        tab[k][1] = __float_as_uint(temb);
        tab[k][2] = __float_as_uint(c1);
        tab[k][3] = __float_as_uint(e);
        tab[k][4] = x0;
        tab[k][5] = x1;
        tab[k][6] = x0 ^ x1 ^ 0x1BD11BDAu;
        tab[k][7] = 0u;
    }
    __syncthreads();
    const int j  = (int)(blockIdx.x * 256u + threadIdx.x);
    const int ns = j / HW;
    const int hw = j - ns * HW;
    const int n  = ns >> 3;
    const int ss = ns & 7;
    const float* sk = skes + (size_t)((n * 3) * 8 + ss) * HW + hw;
    const float w0 = wskes[0], w1 = wskes[1], w2 = wskes[2];
    const float cond = fmaf(w2, sk[2 * 8 * HW], fmaf(w1, sk[8 * HW], w0 * sk[0]));
    const float sT = silT[j];
    float sil = sT;
    float* op = out + j;
#pragma unroll 2
    for (int k = 0; k < NSTEP; ++k) {
        const uint4 ta = *(const uint4*)&tab[k][0];
        const uint4 tb = *(const uint4*)&tab[k][4];
        uint32_t x0 = 0u, x1 = (uint32_t)j;
        tf20(tb.x, tb.y, tb.z, x0, x1);
        const uint32_t bits = x0 ^ x1;
        const float f2 = __uint_as_float((bits >> 9) | 0x3F800000u) - 1.0f;
        const float u  = f2 * 2.0f - 0.99999994f;
        const float t1 = (1.0f - u) * (1.0f + u);
        const float w  = __log2f(t1) * -0.6931472f;
        const bool  lt = w < 5.0f;
        const float ww = lt ? (w - 2.5f) : (__builtin_amdgcn_sqrtf(w) - 3.0f);
        float p =          lt ?  2.81022636e-08f : -0.000200214257f;
        p = fmaf(p, ww,    lt ?  3.43273939e-07f :  0.000100950558f);
        p = fmaf(p, ww,    lt ? -3.5233877e-06f  :  0.00134934322f);
        p = fmaf(p, ww,    lt ? -4.39150654e-06f : -0.00367342844f);
        p = fmaf(p, ww,    lt ?  0.00021858087f  :  0.00573950773f);
        p = fmaf(p, ww,    lt ? -0.00125372503f  : -0.0076224613f);
        p = fmaf(p, ww,    lt ? -0.00417768164f  :  0.00943887047f);
        p = fmaf(p, ww,    lt ?  0.246640727f    :  1.00167406f);
        p = fmaf(p, ww,    lt ?  1.50140941f     :  2.83297682f);
        const float noise = 1.4142135f * (p * u);
        const float d  = fmaf(__uint_as_float(ta.z), noise, __uint_as_float(ta.w) * sT);
        const float s0 = fast_tanh(fmaf(wsil, sil, cond) + __uint_as_float(ta.y));
        *op = s0; op += NELEM;
        sil = fmaf(__uint_as_float(ta.x), s0, d);
    }
}

extern "C" void kernel_launch(void* const* d_in, const int* in_sizes, int n_in,
                              void* d_out, int out_size, void* d_ws, size_t ws_size,
                              hipStream_t stream) {
    const float* skes = (const float*)d_in[0];
    const float* silT = (const float*)d_in[1];
    const float* wsk  = (const float*)d_in[2];
    const float* wsil = (const float*)d_in[3];
    const float* tsc  = (const float*)d_in[4];
    float* out = (float*)d_out;
    (void)in_sizes; (void)n_in; (void)out_size;

    if (ws_size >= WS_NEED) {
        float* dws = (float*)d_ws;
        dim3 gA(NELEM / 256, NSTEP / KPB), bA(256);
        hipLaunchKernelGGL(rng_kernel, gA, bA, 0, stream, silT, dws);
        dim3 gB(SJ / 64), bB(64);
        hipLaunchKernelGGL(scan_kernel, gB, bB, 0, stream,
                           skes, silT, wsk, wsil, tsc, dws, out);
    } else {
        dim3 grid(NELEM / 256), block(256);
        hipLaunchKernelGGL(diffgait_mono, grid, block, 0, stream,
                           skes, silT, wsk, wsil, tsc, out);
    }
}